// Round 4
// baseline (324.674 us; speedup 1.0000x reference)
//
#include <hip/hip_runtime.h>
#include <hip/hip_bf16.h>

typedef __attribute__((ext_vector_type(8))) short short8;
typedef __attribute__((ext_vector_type(4))) float f32x4;

#define T_PRE 64
#define T_FWD 80
#define BATCHN 4096

#define HP 264   // h row pitch (bf16 elems): 256 + 8 pad
#define IP 136   // input row pitch: 128 + 8 pad

// ---- ws layout (ushort offsets) ----
// wrnn [256][384] bf16 : rows j = [W_hh[j] | W_ih[j]]
// wrec [256][384] bf16 : rows j = [A^2[j] | (A*B)[j] | B[j]]     (2-step SS)
// ywt  [2][64][384] bf16: i=0 rows o=[CA | CB | 0], i=1 [CA^2 | CAB | CB]
// f32: brnn[256]=b_ih+b_hh, brec[256]=(A+I)(A_b+B_b), yb[2][64]
// f32 scratch: CA[64][256] (prep1 -> prep2)
#define U_WRNN 0
#define U_WREC 98304
#define U_YW   196608
#define U_FB   245760
#define U_CAF  247040
#define PREP1_N 213504
#define PREP2_N 49280

// Pin a loop-invariant value into VGPRs: "+v" forces materialization and makes
// the value opaque so the compiler cannot re-load it from memory each iter.
// (Round-3 evidence: VGPR_Count=112 < 144 declared weight regs, zero scratch
// traffic -> weights were silently re-streamed from L2 every iteration.)
#define PIN(x) asm volatile("" : "+v"(x))

__device__ __forceinline__ unsigned short bf1(float a) {
  unsigned ua = __float_as_uint(a);
  return (unsigned short)((ua + 0x7fffu + ((ua >> 16) & 1u)) >> 16);
}
__device__ __forceinline__ unsigned pk(float a, float b) {
  __hip_bfloat162 h = __float22bfloat162_rn(make_float2(a, b));
  unsigned u;
  __builtin_memcpy(&u, &h, 4);
  return u;
}
__device__ __forceinline__ float tanh_fast(float x) {
  float e = __expf(2.0f * x);  // saturates correctly for large |x|
  return 1.0f - 2.0f * __builtin_amdgcn_rcpf(e + 1.0f);
}

// prep1: wrnn copy, brnn, CA (f32 scratch), wrec (A^2 | AB | B), brec
__global__ void prep1_kernel(const float* __restrict__ A_w, const float* __restrict__ A_b,
                             const float* __restrict__ B_w, const float* __restrict__ B_b,
                             const float* __restrict__ W_ih, const float* __restrict__ b_ih,
                             const float* __restrict__ W_hh, const float* __restrict__ b_hh,
                             const float* __restrict__ C_w,
                             unsigned short* __restrict__ ws) {
  int i = blockIdx.x * 256 + threadIdx.x;
  float* fb = (float*)(ws + U_FB);
  float* caf = (float*)(ws + U_CAF);
  if (i < 98304) {
    int j = i / 384, k = i - j * 384;
    float v = (k < 256) ? W_hh[j * 256 + k] : W_ih[j * 128 + (k - 256)];
    ws[U_WRNN + i] = bf1(v);
  } else if (i < 98560) {
    int j = i - 98304;
    fb[j] = b_ih[j] + b_hh[j];
  } else if (i < 114944) {
    int ii = i - 98560;
    int o = ii >> 8, j = ii & 255;
    float s = 0.f;
    for (int k = 0; k < 256; ++k) s += C_w[o * 256 + k] * A_w[k * 256 + j];
    caf[ii] = s;
  } else if (i < 213248) {
    int ii = i - 114944;
    int j = ii / 384, k = ii - j * 384;
    float v;
    if (k < 256) {
      float s = 0.f;
      for (int kk = 0; kk < 256; ++kk) s += A_w[j * 256 + kk] * A_w[kk * 256 + k];
      v = s;
    } else if (k < 320) {
      int k2 = k - 256;
      float s = 0.f;
      for (int kk = 0; kk < 256; ++kk) s += A_w[j * 256 + kk] * B_w[kk * 64 + k2];
      v = s;
    } else {
      v = B_w[j * 64 + (k - 320)];
    }
    ws[U_WREC + ii] = bf1(v);
  } else if (i < PREP1_N) {
    int j = i - 213248;
    float s = A_b[j] + B_b[j];
    for (int k = 0; k < 256; ++k) s += A_w[j * 256 + k] * (A_b[k] + B_b[k]);
    fb[256 + j] = s;
  }
}

// prep2: ywt (needs CA from prep1), yb
__global__ void prep2_kernel(const float* __restrict__ A_w, const float* __restrict__ A_b,
                             const float* __restrict__ B_w, const float* __restrict__ B_b,
                             const float* __restrict__ C_w, const float* __restrict__ C_b,
                             unsigned short* __restrict__ ws) {
  int i = blockIdx.x * 256 + threadIdx.x;
  float* fb = (float*)(ws + U_FB);
  const float* caf = (const float*)(ws + U_CAF);
  if (i < 24576) {  // ywt i=0: [CA | CB | 0]
    int o = i / 384, k = i - o * 384;
    float v = 0.f;
    if (k < 256) {
      v = caf[o * 256 + k];
    } else if (k < 320) {
      int k2 = k - 256;
      float s = 0.f;
      for (int kk = 0; kk < 256; ++kk) s += C_w[o * 256 + kk] * B_w[kk * 64 + k2];
      v = s;
    }
    ws[U_YW + i] = bf1(v);
  } else if (i < 49152) {  // ywt i=1: [CA^2 | CAB | CB]
    int ii = i - 24576;
    int o = ii / 384, k = ii - o * 384;
    float v;
    if (k < 256) {
      float s = 0.f;
      for (int kk = 0; kk < 256; ++kk) s += caf[o * 256 + kk] * A_w[kk * 256 + k];
      v = s;
    } else if (k < 320) {
      int k2 = k - 256;
      float s = 0.f;
      for (int kk = 0; kk < 256; ++kk) s += caf[o * 256 + kk] * B_w[kk * 64 + k2];
      v = s;
    } else {
      int k2 = k - 320;
      float s = 0.f;
      for (int kk = 0; kk < 256; ++kk) s += C_w[o * 256 + kk] * B_w[kk * 64 + k2];
      v = s;
    }
    ws[U_YW + 24576 + ii] = bf1(v);
  } else if (i < PREP2_N) {  // yb[2][64]
    int ii = i - 49152;
    int o = ii & 63, which = ii >> 6;
    float s = C_b[o];
    if (which == 0) {
      for (int k = 0; k < 256; ++k) s += C_w[o * 256 + k] * (A_b[k] + B_b[k]);
    } else {
      for (int k = 0; k < 256; ++k)
        s += (caf[o * 256 + k] + C_w[o * 256 + k]) * (A_b[k] + B_b[k]);
    }
    fb[512 + which * 64 + o] = s;
  }
}

// Persistent: 256 blocks x 16 batch rows, 512 threads (8 waves, 2/SIMD).
// launch_bounds(512,2): cap allocator at 256 VGPR/wave so pinned weights fit
// at 2 waves/SIMD. All loop-invariant fragments PIN'd (see macro).
// y-store deferred to after the NEXT barrier so the pre-barrier vmcnt(0) drain
// doesn't wait on store-ack.
__global__ __launch_bounds__(512, 2) void rnn_ss_kernel(
    const float* __restrict__ pre_x, const float* __restrict__ pre_y,
    const float* __restrict__ fwd_x,
    const unsigned short* __restrict__ ws, float* __restrict__ out) {
  __shared__ unsigned short hbuf[2][16 * HP];
  __shared__ unsigned short ibuf[2][16 * IP];

  const int tid = threadIdx.x;
  const int lane = tid & 63;
  const int w = tid >> 6;      // wave 0..7
  const int col = lane & 15;   // batch col (B/D) / A row-in-tile
  const int q = lane >> 4;     // quad
  const int r0 = blockIdx.x * 16;
  const int srow = (tid & 255) >> 4;  // staging batch row 0..15
  const int sc4 = tid & 15;           // staging float4 col 0..15
  const bool xhalf = (tid >= 256);    // waves 4-7 stage x (and x1); 0-3 stage y (and x2)

  // zero hbuf[0] h region -> h0 = 0
#pragma unroll
  for (int it = 0; it < 2; ++it) {
    int i = tid + it * 512;
    int r = i >> 6, c = (i & 63) * 4;
    *(uint2*)&hbuf[0][r * HP + c] = make_uint2(0u, 0u);
  }

  const float* fbias = (const float*)(ws + U_FB);
  int cur = 0;

  // ---------------- encoder tanh-RNN (K = 384) ----------------
  {
    short8 wf[2][12];
#pragma unroll
    for (int mt = 0; mt < 2; ++mt)
#pragma unroll
      for (int kf = 0; kf < 12; ++kf)
        wf[mt][kf] = *(const short8*)(ws + U_WRNN +
                       (size_t)(w * 32 + mt * 16 + col) * 384 + kf * 32 + q * 8);
    f32x4 br[2];
#pragma unroll
    for (int mt = 0; mt < 2; ++mt)
      br[mt] = *(const f32x4*)(fbias + w * 32 + mt * 16 + q * 4);
#pragma unroll
    for (int mt = 0; mt < 2; ++mt) {
#pragma unroll
      for (int kf = 0; kf < 12; ++kf) PIN(wf[mt][kf]);
      PIN(br[mt]);
    }

    // stage xy_0 into ibuf[0]
    {
      f32x4 v = xhalf ? *(const f32x4*)(pre_x + (size_t)(r0 + srow) * 64 + sc4 * 4)
                      : *(const f32x4*)(pre_y + (size_t)(r0 + srow) * 64 + sc4 * 4);
      *(uint2*)&ibuf[0][srow * IP + (xhalf ? 0 : 64) + sc4 * 4] =
          make_uint2(pk(v[0], v[1]), pk(v[2], v[3]));
    }

    for (int t = 0; t < T_PRE; ++t) {
      f32x4 nv;
      if (t < T_PRE - 1) {
        nv = xhalf ? *(const f32x4*)(pre_x + ((size_t)(t + 1) * BATCHN + r0 + srow) * 64 + sc4 * 4)
                   : *(const f32x4*)(pre_y + ((size_t)(t + 1) * BATCHN + r0 + srow) * 64 + sc4 * 4);
      } else {
        // hand off to SS: stage fwd_x[0] at [0,64) and fwd_x[1] at [64,128)
        nv = xhalf ? *(const f32x4*)(fwd_x + (size_t)(r0 + srow) * 64 + sc4 * 4)
                   : *(const f32x4*)(fwd_x + ((size_t)BATCHN + r0 + srow) * 64 + sc4 * 4);
      }
      __syncthreads();  // h_t (hbuf[cur]) and xy_t (ibuf[cur]) visible
      const unsigned short* hc = hbuf[cur];
      const unsigned short* ic = ibuf[cur];
      short8 bfr[12];
#pragma unroll
      for (int kf = 0; kf < 8; ++kf)
        bfr[kf] = *(const short8*)&hc[col * HP + kf * 32 + q * 8];
#pragma unroll
      for (int kf = 8; kf < 12; ++kf)
        bfr[kf] = *(const short8*)&ic[col * IP + (kf - 8) * 32 + q * 8];
      f32x4 acc[2];
#pragma unroll
      for (int mt = 0; mt < 2; ++mt) acc[mt] = br[mt];
#pragma unroll
      for (int kf = 0; kf < 12; ++kf)
#pragma unroll
        for (int mt = 0; mt < 2; ++mt)
          acc[mt] = __builtin_amdgcn_mfma_f32_16x16x32_bf16(wf[mt][kf], bfr[kf], acc[mt], 0, 0, 0);
      unsigned short* hn_ = hbuf[cur ^ 1];
#pragma unroll
      for (int mt = 0; mt < 2; ++mt) {
        float t0 = tanh_fast(acc[mt][0]), t1 = tanh_fast(acc[mt][1]);
        float t2 = tanh_fast(acc[mt][2]), t3 = tanh_fast(acc[mt][3]);
        *(uint2*)&hn_[col * HP + w * 32 + mt * 16 + q * 4] =
            make_uint2(pk(t0, t1), pk(t2, t3));
      }
      *(uint2*)&ibuf[cur ^ 1][srow * IP + (xhalf ? 0 : 64) + sc4 * 4] =
          make_uint2(pk(nv[0], nv[1]), pk(nv[2], nv[3]));
      cur ^= 1;
    }
  }

  // -------- state-space rollout, 2-step unrolled (K = 384) + fused y --------
  {
    short8 rf[2][12];
#pragma unroll
    for (int mt = 0; mt < 2; ++mt)
#pragma unroll
      for (int kf = 0; kf < 12; ++kf)
        rf[mt][kf] = *(const short8*)(ws + U_WREC +
                       (size_t)(w * 32 + mt * 16 + col) * 384 + kf * 32 + q * 8);
    f32x4 brv[2];
#pragma unroll
    for (int mt = 0; mt < 2; ++mt)
      brv[mt] = *(const f32x4*)(fbias + 256 + w * 32 + mt * 16 + q * 4);

    const int yi = w >> 2;   // 0 -> y_{2b+1}, 1 -> y_{2b+2}
    const int yc = w & 3;    // out-dim 16-block
    short8 yf[12];
#pragma unroll
    for (int kf = 0; kf < 12; ++kf)
      yf[kf] = *(const short8*)(ws + U_YW +
                 (size_t)(yi * 64 + yc * 16 + col) * 384 + kf * 32 + q * 8);
    f32x4 ybv = *(const f32x4*)(fbias + 512 + yi * 64 + yc * 16 + q * 4);

#pragma unroll
    for (int mt = 0; mt < 2; ++mt) {
#pragma unroll
      for (int kf = 0; kf < 12; ++kf) PIN(rf[mt][kf]);
      PIN(brv[mt]);
    }
#pragma unroll
    for (int kf = 0; kf < 12; ++kf) PIN(yf[kf]);
    PIN(ybv);

    f32x4 ysav;
    for (int b = 0; b < T_FWD / 2; ++b) {
      f32x4 nv;
      const bool st = (b < T_FWD / 2 - 1);
      if (st)
        nv = *(const f32x4*)(fwd_x +
              ((size_t)(2 * b + 2 + (xhalf ? 0 : 1)) * BATCHN + r0 + srow) * 64 + sc4 * 4);
      __syncthreads();  // h_{2b} (hbuf[cur]) and x_{2b+1},x_{2b+2} (ibuf[cur]) visible
      // deferred y-store for block b-1: full block of compute covers store-ack
      if (b > 0)
        *(f32x4*)(out + ((size_t)(2 * b - 2 + yi) * BATCHN + r0 + col) * 64 + yc * 16 + q * 4) = ysav;
      const unsigned short* hc = hbuf[cur];
      const unsigned short* ic = ibuf[cur];
      short8 bfr[12];
#pragma unroll
      for (int kf = 0; kf < 8; ++kf)
        bfr[kf] = *(const short8*)&hc[col * HP + kf * 32 + q * 8];
#pragma unroll
      for (int kf = 8; kf < 12; ++kf)
        bfr[kf] = *(const short8*)&ic[col * IP + (kf - 8) * 32 + q * 8];
      f32x4 acc[2];
#pragma unroll
      for (int mt = 0; mt < 2; ++mt) acc[mt] = brv[mt];
      f32x4 yacc = ybv;
#pragma unroll
      for (int kf = 0; kf < 12; ++kf) {
        acc[0] = __builtin_amdgcn_mfma_f32_16x16x32_bf16(rf[0][kf], bfr[kf], acc[0], 0, 0, 0);
        acc[1] = __builtin_amdgcn_mfma_f32_16x16x32_bf16(rf[1][kf], bfr[kf], acc[1], 0, 0, 0);
        yacc   = __builtin_amdgcn_mfma_f32_16x16x32_bf16(yf[kf],    bfr[kf], yacc,   0, 0, 0);
      }
      ysav = yacc;
      unsigned short* hn_ = hbuf[cur ^ 1];
#pragma unroll
      for (int mt = 0; mt < 2; ++mt)
        *(uint2*)&hn_[col * HP + w * 32 + mt * 16 + q * 4] =
            make_uint2(pk(acc[mt][0], acc[mt][1]), pk(acc[mt][2], acc[mt][3]));
      if (st)
        *(uint2*)&ibuf[cur ^ 1][srow * IP + (xhalf ? 0 : 64) + sc4 * 4] =
            make_uint2(pk(nv[0], nv[1]), pk(nv[2], nv[3]));
      cur ^= 1;
    }
    // final y (block 39): rows 78+yi
    *(f32x4*)(out + ((size_t)(78 + yi) * BATCHN + r0 + col) * 64 + yc * 16 + q * 4) = ysav;
  }
}

extern "C" void kernel_launch(void* const* d_in, const int* in_sizes, int n_in,
                              void* d_out, int out_size, void* d_ws, size_t ws_size,
                              hipStream_t stream) {
  const float* pre_x = (const float*)d_in[0];
  const float* pre_y = (const float*)d_in[1];
  const float* fwd_x = (const float*)d_in[2];
  const float* A_w   = (const float*)d_in[3];
  const float* A_b   = (const float*)d_in[4];
  const float* B_w   = (const float*)d_in[5];
  const float* B_b   = (const float*)d_in[6];
  const float* C_w   = (const float*)d_in[7];
  const float* C_b   = (const float*)d_in[8];
  const float* W_ih  = (const float*)d_in[9];
  const float* b_ih  = (const float*)d_in[10];
  const float* W_hh  = (const float*)d_in[11];
  const float* b_hh  = (const float*)d_in[12];
  unsigned short* ws = (unsigned short*)d_ws;
  float* out = (float*)d_out;

  prep1_kernel<<<(PREP1_N + 255) / 256, 256, 0, stream>>>(
      A_w, A_b, B_w, B_b, W_ih, b_ih, W_hh, b_hh, C_w, ws);
  prep2_kernel<<<(PREP2_N + 255) / 256, 256, 0, stream>>>(
      A_w, A_b, B_w, B_b, C_w, C_b, ws);
  rnn_ss_kernel<<<BATCHN / 16, 512, 0, stream>>>(pre_x, pre_y, fwd_x, ws, out);
}

// Round 5
// 304.580 us; speedup vs baseline: 1.0660x; 1.0660x over previous
//
#include <hip/hip_runtime.h>
#include <hip/hip_bf16.h>

typedef __attribute__((ext_vector_type(8))) short short8;
typedef __attribute__((ext_vector_type(4))) float f32x4;

#define T_PRE 64
#define T_FWD 80
#define BATCHN 4096

#define HP 264   // h row pitch (bf16 elems): 256 + 8 pad
#define IP 136   // input row pitch: 128 + 8 pad

// ---- ws layout (ushort offsets) ----
// wrnn [256][384] bf16 : rows j = [W_hh[j] | W_ih[j]]
// wrec [256][384] bf16 : rows j = [A^2[j] | (A*B)[j] | B[j]]     (2-step SS)
// ywt  [2][64][384] bf16: i=0 rows o=[CA | CB | 0], i=1 [CA^2 | CAB | CB]
// f32: brnn[256]=b_ih+b_hh, brec[256]=(A+I)(A_b+B_b), yb[2][64]
// f32 scratch: CA[64][256] (prep1 -> prep2)
#define U_WRNN 0
#define U_WREC 98304
#define U_YW   196608
#define U_FB   245760
#define U_CAF  247040
#define PREP1_N 213504
#define PREP2_N 49280

__device__ __forceinline__ unsigned short bf1(float a) {
  unsigned ua = __float_as_uint(a);
  return (unsigned short)((ua + 0x7fffu + ((ua >> 16) & 1u)) >> 16);
}
__device__ __forceinline__ unsigned pk(float a, float b) {
  __hip_bfloat162 h = __float22bfloat162_rn(make_float2(a, b));
  unsigned u;
  __builtin_memcpy(&u, &h, 4);
  return u;
}
__device__ __forceinline__ float tanh_fast(float x) {
  float e = __expf(2.0f * x);  // saturates correctly for large |x|
  return 1.0f - 2.0f * __builtin_amdgcn_rcpf(e + 1.0f);
}

// prep1: wrnn copy, brnn, CA (f32 scratch), wrec (A^2 | AB | B), brec
__global__ void prep1_kernel(const float* __restrict__ A_w, const float* __restrict__ A_b,
                             const float* __restrict__ B_w, const float* __restrict__ B_b,
                             const float* __restrict__ W_ih, const float* __restrict__ b_ih,
                             const float* __restrict__ W_hh, const float* __restrict__ b_hh,
                             const float* __restrict__ C_w,
                             unsigned short* __restrict__ ws) {
  int i = blockIdx.x * 256 + threadIdx.x;
  float* fb = (float*)(ws + U_FB);
  float* caf = (float*)(ws + U_CAF);
  if (i < 98304) {
    int j = i / 384, k = i - j * 384;
    float v = (k < 256) ? W_hh[j * 256 + k] : W_ih[j * 128 + (k - 256)];
    ws[U_WRNN + i] = bf1(v);
  } else if (i < 98560) {
    int j = i - 98304;
    fb[j] = b_ih[j] + b_hh[j];
  } else if (i < 114944) {
    int ii = i - 98560;
    int o = ii >> 8, j = ii & 255;
    float s = 0.f;
    for (int k = 0; k < 256; ++k) s += C_w[o * 256 + k] * A_w[k * 256 + j];
    caf[ii] = s;
  } else if (i < 213248) {
    int ii = i - 114944;
    int j = ii / 384, k = ii - j * 384;
    float v;
    if (k < 256) {
      float s = 0.f;
      for (int kk = 0; kk < 256; ++kk) s += A_w[j * 256 + kk] * A_w[kk * 256 + k];
      v = s;
    } else if (k < 320) {
      int k2 = k - 256;
      float s = 0.f;
      for (int kk = 0; kk < 256; ++kk) s += A_w[j * 256 + kk] * B_w[kk * 64 + k2];
      v = s;
    } else {
      v = B_w[j * 64 + (k - 320)];
    }
    ws[U_WREC + ii] = bf1(v);
  } else if (i < PREP1_N) {
    int j = i - 213248;
    float s = A_b[j] + B_b[j];
    for (int k = 0; k < 256; ++k) s += A_w[j * 256 + k] * (A_b[k] + B_b[k]);
    fb[256 + j] = s;
  }
}

// prep2: ywt (needs CA from prep1), yb
__global__ void prep2_kernel(const float* __restrict__ A_w, const float* __restrict__ A_b,
                             const float* __restrict__ B_w, const float* __restrict__ B_b,
                             const float* __restrict__ C_w, const float* __restrict__ C_b,
                             unsigned short* __restrict__ ws) {
  int i = blockIdx.x * 256 + threadIdx.x;
  float* fb = (float*)(ws + U_FB);
  const float* caf = (const float*)(ws + U_CAF);
  if (i < 24576) {  // ywt i=0: [CA | CB | 0]
    int o = i / 384, k = i - o * 384;
    float v = 0.f;
    if (k < 256) {
      v = caf[o * 256 + k];
    } else if (k < 320) {
      int k2 = k - 256;
      float s = 0.f;
      for (int kk = 0; kk < 256; ++kk) s += C_w[o * 256 + kk] * B_w[kk * 64 + k2];
      v = s;
    }
    ws[U_YW + i] = bf1(v);
  } else if (i < 49152) {  // ywt i=1: [CA^2 | CAB | CB]
    int ii = i - 24576;
    int o = ii / 384, k = ii - o * 384;
    float v;
    if (k < 256) {
      float s = 0.f;
      for (int kk = 0; kk < 256; ++kk) s += caf[o * 256 + kk] * A_w[kk * 256 + k];
      v = s;
    } else if (k < 320) {
      int k2 = k - 256;
      float s = 0.f;
      for (int kk = 0; kk < 256; ++kk) s += caf[o * 256 + kk] * B_w[kk * 64 + k2];
      v = s;
    } else {
      int k2 = k - 320;
      float s = 0.f;
      for (int kk = 0; kk < 256; ++kk) s += C_w[o * 256 + kk] * B_w[kk * 64 + k2];
      v = s;
    }
    ws[U_YW + 24576 + ii] = bf1(v);
  } else if (i < PREP2_N) {  // yb[2][64]
    int ii = i - 49152;
    int o = ii & 63, which = ii >> 6;
    float s = C_b[o];
    if (which == 0) {
      for (int k = 0; k < 256; ++k) s += C_w[o * 256 + k] * (A_b[k] + B_b[k]);
    } else {
      for (int k = 0; k < 256; ++k)
        s += (caf[o * 256 + k] + C_w[o * 256 + k]) * (A_b[k] + B_b[k]);
    }
    fb[512 + which * 64 + o] = s;
  }
}

// Persistent: 256 blocks x 16 batch rows, 512 threads (8 waves, 2/SIMD).
// amdgpu_waves_per_eu(2,2): occupancy is hard-capped at 1 block/CU anyway
// (8-wave block), so tell the allocator max=2 waves/EU -> it budgets 256
// VGPRs and keeps all weight fragments live instead of re-materializing
// them from L2 (round-3 evidence: VGPR_Count=112 << 156 declared frags,
// SS blocks ~550cy over MFMA+barrier model).
// y-store deferred one block: issued right after the NEXT barrier so a full
// block of compute covers the store-ack before the pre-barrier vmcnt(0) drain.
__global__ __launch_bounds__(512) __attribute__((amdgpu_waves_per_eu(2, 2)))
void rnn_ss_kernel(
    const float* __restrict__ pre_x, const float* __restrict__ pre_y,
    const float* __restrict__ fwd_x,
    const unsigned short* __restrict__ ws, float* __restrict__ out) {
  __shared__ unsigned short hbuf[2][16 * HP];
  __shared__ unsigned short ibuf[2][16 * IP];

  const int tid = threadIdx.x;
  const int lane = tid & 63;
  const int w = tid >> 6;      // wave 0..7
  const int col = lane & 15;   // batch col (B/D) / A row-in-tile
  const int q = lane >> 4;     // quad
  const int r0 = blockIdx.x * 16;
  const int srow = (tid & 255) >> 4;  // staging batch row 0..15
  const int sc4 = tid & 15;           // staging float4 col 0..15
  const bool xhalf = (tid >= 256);    // waves 4-7 stage x (and x1); 0-3 stage y (and x2)

  // zero hbuf[0] h region -> h0 = 0
#pragma unroll
  for (int it = 0; it < 2; ++it) {
    int i = tid + it * 512;
    int r = i >> 6, c = (i & 63) * 4;
    *(uint2*)&hbuf[0][r * HP + c] = make_uint2(0u, 0u);
  }

  const float* fbias = (const float*)(ws + U_FB);
  int cur = 0;

  // ---------------- encoder tanh-RNN (K = 384) ----------------
  {
    short8 wf[2][12];
#pragma unroll
    for (int mt = 0; mt < 2; ++mt)
#pragma unroll
      for (int kf = 0; kf < 12; ++kf)
        wf[mt][kf] = *(const short8*)(ws + U_WRNN +
                       (size_t)(w * 32 + mt * 16 + col) * 384 + kf * 32 + q * 8);
    f32x4 br[2];
#pragma unroll
    for (int mt = 0; mt < 2; ++mt)
      br[mt] = *(const f32x4*)(fbias + w * 32 + mt * 16 + q * 4);

    // stage xy_0 into ibuf[0]
    {
      f32x4 v = xhalf ? *(const f32x4*)(pre_x + (size_t)(r0 + srow) * 64 + sc4 * 4)
                      : *(const f32x4*)(pre_y + (size_t)(r0 + srow) * 64 + sc4 * 4);
      *(uint2*)&ibuf[0][srow * IP + (xhalf ? 0 : 64) + sc4 * 4] =
          make_uint2(pk(v[0], v[1]), pk(v[2], v[3]));
    }

    for (int t = 0; t < T_PRE; ++t) {
      f32x4 nv;
      if (t < T_PRE - 1) {
        nv = xhalf ? *(const f32x4*)(pre_x + ((size_t)(t + 1) * BATCHN + r0 + srow) * 64 + sc4 * 4)
                   : *(const f32x4*)(pre_y + ((size_t)(t + 1) * BATCHN + r0 + srow) * 64 + sc4 * 4);
      } else {
        // hand off to SS: stage fwd_x[0] at [0,64) and fwd_x[1] at [64,128)
        nv = xhalf ? *(const f32x4*)(fwd_x + (size_t)(r0 + srow) * 64 + sc4 * 4)
                   : *(const f32x4*)(fwd_x + ((size_t)BATCHN + r0 + srow) * 64 + sc4 * 4);
      }
      __syncthreads();  // h_t (hbuf[cur]) and xy_t (ibuf[cur]) visible
      const unsigned short* hc = hbuf[cur];
      const unsigned short* ic = ibuf[cur];
      short8 bfr[12];
#pragma unroll
      for (int kf = 0; kf < 8; ++kf)
        bfr[kf] = *(const short8*)&hc[col * HP + kf * 32 + q * 8];
#pragma unroll
      for (int kf = 8; kf < 12; ++kf)
        bfr[kf] = *(const short8*)&ic[col * IP + (kf - 8) * 32 + q * 8];
      f32x4 acc[2];
#pragma unroll
      for (int mt = 0; mt < 2; ++mt) acc[mt] = br[mt];
#pragma unroll
      for (int kf = 0; kf < 12; ++kf)
#pragma unroll
        for (int mt = 0; mt < 2; ++mt)
          acc[mt] = __builtin_amdgcn_mfma_f32_16x16x32_bf16(wf[mt][kf], bfr[kf], acc[mt], 0, 0, 0);
      unsigned short* hn_ = hbuf[cur ^ 1];
#pragma unroll
      for (int mt = 0; mt < 2; ++mt) {
        float t0 = tanh_fast(acc[mt][0]), t1 = tanh_fast(acc[mt][1]);
        float t2 = tanh_fast(acc[mt][2]), t3 = tanh_fast(acc[mt][3]);
        *(uint2*)&hn_[col * HP + w * 32 + mt * 16 + q * 4] =
            make_uint2(pk(t0, t1), pk(t2, t3));
      }
      *(uint2*)&ibuf[cur ^ 1][srow * IP + (xhalf ? 0 : 64) + sc4 * 4] =
          make_uint2(pk(nv[0], nv[1]), pk(nv[2], nv[3]));
      cur ^= 1;
    }
  }

  // -------- state-space rollout, 2-step unrolled (K = 384) + fused y --------
  {
    short8 rf[2][12];
#pragma unroll
    for (int mt = 0; mt < 2; ++mt)
#pragma unroll
      for (int kf = 0; kf < 12; ++kf)
        rf[mt][kf] = *(const short8*)(ws + U_WREC +
                       (size_t)(w * 32 + mt * 16 + col) * 384 + kf * 32 + q * 8);
    f32x4 brv[2];
#pragma unroll
    for (int mt = 0; mt < 2; ++mt)
      brv[mt] = *(const f32x4*)(fbias + 256 + w * 32 + mt * 16 + q * 4);

    const int yi = w >> 2;   // 0 -> y_{2b+1}, 1 -> y_{2b+2}
    const int yc = w & 3;    // out-dim 16-block
    short8 yf[12];
#pragma unroll
    for (int kf = 0; kf < 12; ++kf)
      yf[kf] = *(const short8*)(ws + U_YW +
                 (size_t)(yi * 64 + yc * 16 + col) * 384 + kf * 32 + q * 8);
    f32x4 ybv = *(const f32x4*)(fbias + 512 + yi * 64 + yc * 16 + q * 4);

    f32x4 ysav;
    for (int b = 0; b < T_FWD / 2; ++b) {
      f32x4 nv;
      const bool st = (b < T_FWD / 2 - 1);
      if (st)
        nv = *(const f32x4*)(fwd_x +
              ((size_t)(2 * b + 2 + (xhalf ? 0 : 1)) * BATCHN + r0 + srow) * 64 + sc4 * 4);
      __syncthreads();  // h_{2b} (hbuf[cur]) and x_{2b+1},x_{2b+2} (ibuf[cur]) visible
      // deferred y-store for block b-1: a full block of compute covers store-ack
      if (b > 0)
        *(f32x4*)(out + ((size_t)(2 * b - 2 + yi) * BATCHN + r0 + col) * 64 + yc * 16 + q * 4) = ysav;
      const unsigned short* hc = hbuf[cur];
      const unsigned short* ic = ibuf[cur];
      short8 bfr[12];
#pragma unroll
      for (int kf = 0; kf < 8; ++kf)
        bfr[kf] = *(const short8*)&hc[col * HP + kf * 32 + q * 8];
#pragma unroll
      for (int kf = 8; kf < 12; ++kf)
        bfr[kf] = *(const short8*)&ic[col * IP + (kf - 8) * 32 + q * 8];
      f32x4 acc[2];
#pragma unroll
      for (int mt = 0; mt < 2; ++mt) acc[mt] = brv[mt];
      f32x4 yacc = ybv;
#pragma unroll
      for (int kf = 0; kf < 12; ++kf) {
        acc[0] = __builtin_amdgcn_mfma_f32_16x16x32_bf16(rf[0][kf], bfr[kf], acc[0], 0, 0, 0);
        acc[1] = __builtin_amdgcn_mfma_f32_16x16x32_bf16(rf[1][kf], bfr[kf], acc[1], 0, 0, 0);
        yacc   = __builtin_amdgcn_mfma_f32_16x16x32_bf16(yf[kf],    bfr[kf], yacc,   0, 0, 0);
      }
      ysav = yacc;
      unsigned short* hn_ = hbuf[cur ^ 1];
#pragma unroll
      for (int mt = 0; mt < 2; ++mt)
        *(uint2*)&hn_[col * HP + w * 32 + mt * 16 + q * 4] =
            make_uint2(pk(acc[mt][0], acc[mt][1]), pk(acc[mt][2], acc[mt][3]));
      if (st)
        *(uint2*)&ibuf[cur ^ 1][srow * IP + (xhalf ? 0 : 64) + sc4 * 4] =
            make_uint2(pk(nv[0], nv[1]), pk(nv[2], nv[3]));
      cur ^= 1;
    }
    // final y (block 39): rows 78+yi
    *(f32x4*)(out + ((size_t)(78 + yi) * BATCHN + r0 + col) * 64 + yc * 16 + q * 4) = ysav;
  }
}

extern "C" void kernel_launch(void* const* d_in, const int* in_sizes, int n_in,
                              void* d_out, int out_size, void* d_ws, size_t ws_size,
                              hipStream_t stream) {
  const float* pre_x = (const float*)d_in[0];
  const float* pre_y = (const float*)d_in[1];
  const float* fwd_x = (const float*)d_in[2];
  const float* A_w   = (const float*)d_in[3];
  const float* A_b   = (const float*)d_in[4];
  const float* B_w   = (const float*)d_in[5];
  const float* B_b   = (const float*)d_in[6];
  const float* C_w   = (const float*)d_in[7];
  const float* C_b   = (const float*)d_in[8];
  const float* W_ih  = (const float*)d_in[9];
  const float* b_ih  = (const float*)d_in[10];
  const float* W_hh  = (const float*)d_in[11];
  const float* b_hh  = (const float*)d_in[12];
  unsigned short* ws = (unsigned short*)d_ws;
  float* out = (float*)d_out;

  prep1_kernel<<<(PREP1_N + 255) / 256, 256, 0, stream>>>(
      A_w, A_b, B_w, B_b, W_ih, b_ih, W_hh, b_hh, C_w, ws);
  prep2_kernel<<<(PREP2_N + 255) / 256, 256, 0, stream>>>(
      A_w, A_b, B_w, B_b, C_w, C_b, ws);
  rnn_ss_kernel<<<BATCHN / 16, 512, 0, stream>>>(pre_x, pre_y, fwd_x, ws, out);
}